// Round 13
// baseline (308.207 us; speedup 1.0000x reference)
//
#include <hip/hip_runtime.h>
#include <math.h>

#define N_NODES 100000
#define N_EDGES 3200000
#define B_GRAPHS 500
#define K_TOP 30
#define F_INN 128
#define H1C 64
#define NUM_CLASSES 18
#define XC 65               // H1 + 1
#define P_LEN (K_TOP * XC)  // 1950
#define C3_OUT 16
#define C3_K 97
#define C3_L 20
#define P2_L 10
#define C4_OUT 32
#define C4_K 5
#define C4_L 6
#define FC1_IN 192
#define FC1_OUT 128

#define BK_SHIFT 7
#define BK_NODES 128                               // nodes per bucket
#define NBKT ((N_NODES + BK_NODES - 1) / BK_NODES) // 782
#define BSTRIDE 5120                               // slots per bucket (mean 4096 + 16 sigma)
#define MS_EPT 64                                  // edges per thread in mscatter
#define MS_EPB (256 * MS_EPT)                      // 16384 edges per block -> 196 blocks

#define REG_B 544                                  // bytes per (t,h) LDS region (512 + 32 skew)

typedef __attribute__((ext_vector_type(8))) short bf16x8;
typedef __attribute__((ext_vector_type(4))) float f32x4;
typedef __attribute__((ext_vector_type(2))) unsigned int u32x2;

// bf16 helpers
static __device__ __forceinline__ unsigned short f2bf(float f) {
    unsigned int u = __float_as_uint(f);
    u += 0x7FFFu + ((u >> 16) & 1u);   // round to nearest even
    return (unsigned short)(u >> 16);
}

// ------- multi-split scatter: ebkt[b*BSTRIDE + slot] = (row<<7 | col_local) -------
__global__ __launch_bounds__(256) void k_mscatter(const int* __restrict__ row,
                                                  const int* __restrict__ col,
                                                  int* __restrict__ gcur,
                                                  unsigned int* __restrict__ ebkt) {
    __shared__ int hist[NBKT];
    __shared__ int base[NBKT];
    int tid = threadIdx.x;
    for (int i = tid; i < NBKT; i += 256) hist[i] = 0;
    __syncthreads();
    unsigned int pk[MS_EPT];   // (bucket<<12) | rank, or sentinel
    unsigned int pay[MS_EPT];  // (row<<7) | col_local
    int e0q = blockIdx.x * (MS_EPB / 4);   // int4 index base
#pragma unroll
    for (int j = 0; j < MS_EPT / 4; ++j) {
        int q = e0q + j * 256 + tid;
        bool ok = (q * 4) < N_EDGES;       // N_EDGES % 4 == 0: all-or-nothing
        int4 r4 = ok ? ((const int4*)row)[q] : make_int4(0, 0, 0, 0);
        int4 c4 = ok ? ((const int4*)col)[q] : make_int4(0, 0, 0, 0);
#pragma unroll
        for (int k = 0; k < 4; ++k) {
            int jj = j * 4 + k;
            pk[jj] = 0xFFFFFFFFu;
            int r = k == 0 ? r4.x : k == 1 ? r4.y : k == 2 ? r4.z : r4.w;
            int c = k == 0 ? c4.x : k == 1 ? c4.y : k == 2 ? c4.z : c4.w;
            if (ok && r != c) {
                int b = c >> BK_SHIFT;
                int rank = atomicAdd(&hist[b], 1);
                pk[jj] = ((unsigned int)b << 12) | (unsigned int)rank;   // rank < 4096 (mean 21)
                pay[jj] = ((unsigned int)r << BK_SHIFT) | (unsigned int)(c & (BK_NODES - 1));
            }
        }
    }
    __syncthreads();
    for (int i = tid; i < NBKT; i += 256)
        base[i] = hist[i] ? (i * BSTRIDE + atomicAdd(&gcur[i], hist[i])) : 0;
    __syncthreads();
#pragma unroll
    for (int j = 0; j < MS_EPT; ++j) {
        if (pk[j] != 0xFFFFFFFFu) {
            int b = pk[j] >> 12;
            int rank = pk[j] & 0xFFF;
            ebkt[base[b] + rank] = pay[j];
        }
    }
}

// ------- merged CSR build + gstart table + xw1 MFMA (block-local fusion) -------
__global__ __launch_bounds__(256) void k_csrw(const unsigned int* __restrict__ ebkt,
                                              const int* __restrict__ gcur,
                                              const int* __restrict__ batch,
                                              const float* __restrict__ x,
                                              const float* __restrict__ W1,
                                              float* __restrict__ dis,
                                              int2* __restrict__ rowse,
                                              int* __restrict__ erow,
                                              int* __restrict__ gstart,
                                              unsigned short* __restrict__ xw) {
    __shared__ __align__(16) char ubuf[BSTRIDE * 4];   // 20480B: ebs, then w1s
    __shared__ int cnt[BK_NODES];
    __shared__ int s[256];
    __shared__ int cur[BK_NODES];
    __shared__ float diss[BK_NODES];
    int b = blockIdx.x, t = threadIdx.x;
    unsigned int* ebs = (unsigned int*)ubuf;
    if (t < BK_NODES) {
        cnt[t] = 0;
        int node = b * BK_NODES + t;
        if (node < N_NODES) {   // graph boundary marking (disjoint writes across blocks)
            int bc = batch[node];
            int bp = node ? batch[node - 1] : -1;
            for (int g = bp + 1; g <= bc; ++g) gstart[g] = node;
            if (node == N_NODES - 1)
                for (int g = bc + 1; g <= B_GRAPHS; ++g) gstart[g] = N_NODES;
        }
    }
    __syncthreads();
    int n = gcur[b];
    int lo = b * BSTRIDE;
    for (int i = t; i < n; i += 256) {
        unsigned int pk = ebkt[lo + i];
        ebs[i] = pk;
        atomicAdd(&cnt[pk & (BK_NODES - 1)], 1);
    }
    __syncthreads();
    int v = (t < BK_NODES) ? cnt[t] : 0;
    s[t] = v;
    __syncthreads();
    for (int off = 1; off < BK_NODES; off <<= 1) {
        int add = (t >= off) ? s[t - off] : 0;
        __syncthreads();
        s[t] += add;
        __syncthreads();
    }
    int ex = s[t] - v;
    if (t < BK_NODES) {
        float dv = rsqrtf((float)v + 1.0f);
        diss[t] = dv;
        int node = b * BK_NODES + t;
        if (node < N_NODES) {
            dis[node] = dv;
            rowse[node] = make_int2(lo + ex, lo + ex + v);
        }
        cur[t] = lo + ex;
    }
    __syncthreads();
    for (int i = t; i < n; i += 256) {
        unsigned int pk = ebs[i];
        int cl = pk & (BK_NODES - 1);
        int slot = atomicAdd(&cur[cl], 1);
        erow[slot] = (int)((pk >> BK_SHIFT) << 7);   // byte offset into bf16 rows (128B)
    }
    __syncthreads();   // ebs dead: safe to overwrite with w1s
    // ---- xw1 phase: xws rows for this block's 128 nodes ----
    unsigned short* w1s = (unsigned short*)ubuf;   // 16KB
    if (b == 0 && t < 32)
        ((unsigned int*)(xw + (size_t)N_NODES * H1C))[t] = 0;   // zero pad row
    for (int idx = t; idx < 16 * 64 * 8; idx += 256) {
        int f = idx >> 9;
        int l = (idx >> 3) & 63;
        int j = idx & 7;
        int kq = f >> 2, t4 = f & 3;
        int k = kq * 32 + ((l >> 4) << 3) + j;
        int nn = t4 * 16 + (l & 15);
        w1s[idx] = f2bf(W1[k * H1C + nn]);
    }
    __syncthreads();
    int wave = t >> 6;
    int lane = t & 63;
    int quad = lane >> 4;
    int m = lane & 15;

    bf16x8 bw[16];
#pragma unroll
    for (int f = 0; f < 16; ++f)
        bw[f] = *(const bf16x8*)&w1s[(f * 64 + lane) * 8];

#pragma unroll
    for (int rt = 0; rt < 2; ++rt) {
        int wrow0 = b * BK_NODES + rt * 64 + wave * 16;
        f32x4 acc[4];
#pragma unroll
        for (int tt = 0; tt < 4; ++tt) acc[tt] = (f32x4){0.f, 0.f, 0.f, 0.f};

        int rowA = wrow0 + m;
        size_t ra = (size_t)(rowA < N_NODES ? rowA : N_NODES - 1);
#pragma unroll
        for (int kq = 0; kq < 4; ++kq) {
            const float* xp = x + ra * F_INN + kq * 32 + quad * 8;
            float4 f0 = ((const float4*)xp)[0];
            float4 f1 = ((const float4*)xp)[1];
            bf16x8 a;
            a[0] = (short)f2bf(f0.x); a[1] = (short)f2bf(f0.y);
            a[2] = (short)f2bf(f0.z); a[3] = (short)f2bf(f0.w);
            a[4] = (short)f2bf(f1.x); a[5] = (short)f2bf(f1.y);
            a[6] = (short)f2bf(f1.z); a[7] = (short)f2bf(f1.w);
#pragma unroll
            for (int tt = 0; tt < 4; ++tt)
                acc[tt] = __builtin_amdgcn_mfma_f32_16x16x32_bf16(a, bw[kq * 4 + tt], acc[tt], 0, 0, 0);
        }
#pragma unroll
        for (int r = 0; r < 4; ++r) {
            int rowD = wrow0 + quad * 4 + r;
            if (rowD < N_NODES) {
                float dsc = diss[rowD - b * BK_NODES];
#pragma unroll
                for (int tt = 0; tt < 4; ++tt)
                    xw[(size_t)rowD * H1C + tt * 16 + m] = f2bf(acc[tt][r] * dsc);
            }
        }
    }
}

// ------- conv1 gather via MFMA aggregation (R7-proven non-pipelined form) -------
__global__ __launch_bounds__(256) void k_agg1m(const int2* __restrict__ rowse,
                                               const int* __restrict__ erow,
                                               const unsigned short* __restrict__ xws,
                                               const float* __restrict__ dis,
                                               const float* __restrict__ b1,
                                               const float* __restrict__ W2,
                                               float* __restrict__ x1,
                                               float* __restrict__ xws2) {
    __shared__ __align__(16) char slds[4][8 * REG_B];   // 17408 B
    int tid = threadIdx.x;
    int wave = tid >> 6;
    int lane = tid & 63;
    int wid = blockIdx.x * 4 + wave;   // wid < N_NODES always (exact grid)
    int grp = lane >> 3;   // 0..7  -> edge-within-octet
    int sub = lane & 7;    // 0..7  -> 16B chunk of the 128B row
    int2 se = rowse[wid];
    int base = se.x, endp = se.y;
    int nE = endp - base;
    const char* xb = (const char*)xws;
    const int ZR = N_NODES << 7;   // zero row pad (L1-cached)

    char* wreg = &slds[wave][0];
    char* dst0 = wreg + ((sub >> 1) * 2 + ((grp >> 2) & 1)) * REG_B + (grp & 3) * 32 + (sub & 1) * 16;
    unsigned int trb = (unsigned int)(size_t)wreg +
                       (unsigned int)(((lane >> 4) * 64 + (lane & 15)) * 2);

    bf16x8 aones;
#pragma unroll
    for (int i = 0; i < 8; ++i) aones[i] = (short)0x3F80;   // bf16 1.0

    f32x4 ac0 = (f32x4){0.f, 0.f, 0.f, 0.f};
    f32x4 ac1 = ac0, ac2 = ac0, ac3 = ac0;

    for (int w0 = 0; w0 < nE; w0 += 64) {
        int idx = base + w0 + lane;
        int myoff = (idx < endp) ? erow[idx] : ZR;
#pragma unroll
        for (int hf = 0; hf < 2; ++hf) {
            if (w0 + hf * 32 < nE) {   // wave-uniform
#pragma unroll
                for (int ii = 0; ii < 4; ++ii) {
                    int o = __shfl(myoff, hf * 32 + ii * 8 + grp);
                    uint4 v = ((const uint4*)(xb + o))[sub];
                    *(uint4*)(dst0 + ii * 128) = v;
                }
                asm volatile("s_waitcnt lgkmcnt(0)" ::: "memory");
                __builtin_amdgcn_sched_barrier(0);
                u32x2 q0, q1, q2, q3, q4, q5, q6, q7;
                asm volatile("ds_read_b64_tr_b16 %0, %1 offset:0"    : "=v"(q0) : "v"(trb) : "memory");
                asm volatile("ds_read_b64_tr_b16 %0, %1 offset:544"  : "=v"(q1) : "v"(trb) : "memory");
                asm volatile("ds_read_b64_tr_b16 %0, %1 offset:1088" : "=v"(q2) : "v"(trb) : "memory");
                asm volatile("ds_read_b64_tr_b16 %0, %1 offset:1632" : "=v"(q3) : "v"(trb) : "memory");
                asm volatile("ds_read_b64_tr_b16 %0, %1 offset:2176" : "=v"(q4) : "v"(trb) : "memory");
                asm volatile("ds_read_b64_tr_b16 %0, %1 offset:2720" : "=v"(q5) : "v"(trb) : "memory");
                asm volatile("ds_read_b64_tr_b16 %0, %1 offset:3264" : "=v"(q6) : "v"(trb) : "memory");
                asm volatile("ds_read_b64_tr_b16 %0, %1 offset:3808" : "=v"(q7) : "v"(trb) : "memory");
                asm volatile("s_waitcnt lgkmcnt(0)" ::: "memory");
                __builtin_amdgcn_sched_barrier(0);
                union FU { bf16x8 f; unsigned int d[4]; };
                FU f0, f1, f2, f3;
                f0.d[0] = q0.x; f0.d[1] = q0.y; f0.d[2] = q1.x; f0.d[3] = q1.y;
                f1.d[0] = q2.x; f1.d[1] = q2.y; f1.d[2] = q3.x; f1.d[3] = q3.y;
                f2.d[0] = q4.x; f2.d[1] = q4.y; f2.d[2] = q5.x; f2.d[3] = q5.y;
                f3.d[0] = q6.x; f3.d[1] = q6.y; f3.d[2] = q7.x; f3.d[3] = q7.y;
                ac0 = __builtin_amdgcn_mfma_f32_16x16x32_bf16(aones, f0.f, ac0, 0, 0, 0);
                ac1 = __builtin_amdgcn_mfma_f32_16x16x32_bf16(aones, f1.f, ac1, 0, 0, 0);
                ac2 = __builtin_amdgcn_mfma_f32_16x16x32_bf16(aones, f2.f, ac2, 0, 0, 0);
                ac3 = __builtin_amdgcn_mfma_f32_16x16x32_bf16(aones, f3.f, ac3, 0, 0, 0);
            }
        }
    }
    float v0s = __shfl(ac0[0], lane & 15);
    float v1s = __shfl(ac1[0], lane & 15);
    float v2s = __shfl(ac2[0], lane & 15);
    float v3s = __shfl(ac3[0], lane & 15);
    int ts = lane >> 4;
    float aggv = ts == 0 ? v0s : (ts == 1 ? v1s : (ts == 2 ? v2s : v3s));
    float d = dis[wid];
    unsigned int su = xws[(size_t)wid * H1C + lane];   // self row (pre-scaled by dis[wid])
    float self = __uint_as_float(su << 16);
    float v = tanhf(d * (aggv + self) + b1[lane]);
    x1[(size_t)wid * H1C + lane] = v;
    float s = v * W2[lane];
#pragma unroll
    for (int off = 1; off < 64; off <<= 1) s += __shfl_xor(s, off);
    if (lane == 0) xws2[wid] = d * s;   // pre-scaled by dis
}

// ------- fused conv2 + sort-pool + head: one block per graph, 1024 threads -------
// 16 waves: conv2 gathers 128 nodes/pass (4x the TLP of the 256-thread form),
// p-tile/conv3 go 4x wider, fc1 splits each 192-dot across 8 lanes.
__global__ __launch_bounds__(1024) void k_poolhead(const int* __restrict__ gstart,
                                                  const float* __restrict__ x1,
                                                  const int2* __restrict__ rowse,
                                                  const int* __restrict__ erow,
                                                  const float* __restrict__ xws2,
                                                  const float* __restrict__ dis,
                                                  const float* __restrict__ b2,
                                                  const float* __restrict__ w3, const float* __restrict__ b3,
                                                  const float* __restrict__ w4, const float* __restrict__ b4,
                                                  const float* __restrict__ fw1, const float* __restrict__ fb1,
                                                  const float* __restrict__ fw2, const float* __restrict__ fb2,
                                                  float* __restrict__ out) {
    __shared__ float x2s[512];
    __shared__ int sel[K_TOP];
    __shared__ float ps[P_LEN];
    __shared__ float h1s[C3_OUT * C3_L];
    __shared__ float h2s[C3_OUT * P2_L];
    __shared__ float h3s[FC1_IN];
    __shared__ float lls[FC1_OUT];
    __shared__ float outs[NUM_CLASSES];
    int g = blockIdx.x, tid = threadIdx.x;
    int start = gstart[g];
    int end = gstart[g + 1];
    int count = end - start;
    if (count > 512) count = 512;
    int wave = tid >> 6, lane = tid & 63;
    // conv2 wave-parallel: 16 waves x 8 nodes/wave, 8 lanes per node
    {
        float b2v = b2[0];
        int grp8 = lane >> 3, sub8 = lane & 7;
        for (int t0 = 0; t0 < count; t0 += 128) {
            int li = t0 + wave * 8 + grp8;
            float acc = 0.0f;
            int node = start + li;
            if (li < count) {
                int2 se = rowse[node];
                for (int i = se.x + sub8; i < se.y; i += 8)
                    acc += xws2[erow[i] >> 7];
            }
            acc += __shfl_xor(acc, 1);
            acc += __shfl_xor(acc, 2);
            acc += __shfl_xor(acc, 4);
            if (li < count && sub8 == 0)
                x2s[li] = tanhf(dis[node] * (acc + xws2[node]) + b2v);
        }
    }
    __syncthreads();
    if (wave == 0) {
        unsigned long long k[8];
#pragma unroll
        for (int i = 0; i < 8; ++i) {
            int idx = i * 64 + lane;
            unsigned long long key = 0ULL;
            if (idx < count) {
                unsigned int bits = __float_as_uint(x2s[idx]);
                unsigned int u = (bits & 0x80000000u) ? ~bits : (bits | 0x80000000u);
                key = ((unsigned long long)u << 32) | (unsigned int)(~(unsigned int)(start + idx));
            }
            k[i] = key;
        }
        int kk = count < K_TOP ? count : K_TOP;
        for (int j = 0; j < kk; ++j) {
            unsigned long long best = k[0];
#pragma unroll
            for (int i = 1; i < 8; ++i) if (k[i] > best) best = k[i];
#pragma unroll
            for (int off = 32; off; off >>= 1) {
                unsigned long long o = __shfl_xor(best, off);
                if (o > best) best = o;
            }
            int node = (int)(~(unsigned int)(best & 0xFFFFFFFFULL));
#pragma unroll
            for (int i = 0; i < 8; ++i) if (k[i] == best) k[i] = 0ULL;
            if (lane == 0) sel[j] = node;
        }
        if (lane >= kk && lane < K_TOP) sel[lane] = -1;
    }
    __syncthreads();
    for (int t = tid; t < P_LEN; t += 1024) {
        int j = t / XC, c = t - j * XC;
        int node = sel[j];
        float v = 0.0f;
        if (node >= 0) v = (c < H1C) ? x1[(size_t)node * H1C + c] : x2s[node - start];
        ps[t] = v;
    }
    __syncthreads();
    if (tid < C3_OUT * C3_L) {
        int oc = tid / C3_L, pos = tid % C3_L;
        float s = b3[oc];
        const float* w = w3 + oc * C3_K;
        int base = pos * C3_K;
        for (int k = 0; k < C3_K; ++k) s += ps[base + k] * w[k];
        h1s[tid] = fmaxf(s, 0.0f);
    }
    __syncthreads();
    if (tid < C3_OUT * P2_L) {
        int oc = tid / P2_L, pos = tid % P2_L;
        h2s[tid] = fmaxf(h1s[oc * C3_L + 2 * pos], h1s[oc * C3_L + 2 * pos + 1]);
    }
    __syncthreads();
    if (tid < C4_OUT * C4_L) {
        int oc = tid / C4_L, pos = tid % C4_L;
        float s = b4[oc];
        for (int ic = 0; ic < C3_OUT; ++ic)
#pragma unroll
            for (int k = 0; k < C4_K; ++k)
                s += h2s[ic * P2_L + pos + k] * w4[oc * C3_OUT * C4_K + ic * C4_K + k];
        h3s[oc * C4_L + pos] = fmaxf(s, 0.0f);
    }
    __syncthreads();
    {   // fc1: 128 outputs x 8 lanes each (24 elems/lane, shfl-tree reduce)
        int o = tid >> 3, p = tid & 7;
        float s = 0.0f;
        for (int i = p * 24; i < p * 24 + 24; ++i) s += h3s[i] * fw1[i * FC1_OUT + o];
        s += __shfl_xor(s, 1);
        s += __shfl_xor(s, 2);
        s += __shfl_xor(s, 4);
        if (p == 0) {
            float v = fmaxf(s + fb1[o], 0.0f);
            lls[o] = v;
            out[2 * B_GRAPHS * NUM_CLASSES + (size_t)g * FC1_OUT + o] = v;
        }
    }
    __syncthreads();
    if (tid < NUM_CLASSES * 8) {   // fc2: 18 outputs x 8 lanes (16 elems/lane)
        int o = tid >> 3, p = tid & 7;
        float s = 0.0f;
        for (int j = p * 16; j < p * 16 + 16; ++j) s += lls[j] * fw2[j * NUM_CLASSES + o];
        s += __shfl_xor(s, 1);
        s += __shfl_xor(s, 2);
        s += __shfl_xor(s, 4);
        if (p == 0) {
            float v = s + fb2[o];
            outs[o] = v;
            out[B_GRAPHS * NUM_CLASSES + (size_t)g * NUM_CLASSES + o] = v;
        }
    }
    __syncthreads();
    if (tid < NUM_CLASSES) {
        float m = -INFINITY;
        for (int k2 = 0; k2 < NUM_CLASSES; ++k2) m = fmaxf(m, outs[k2]);
        float se = 0.0f;
        for (int k2 = 0; k2 < NUM_CLASSES; ++k2) se += expf(outs[k2] - m);
        out[(size_t)g * NUM_CLASSES + tid] = outs[tid] - m - logf(se);
    }
}

extern "C" void kernel_launch(void* const* d_in, const int* in_sizes, int n_in,
                              void* d_out, int out_size, void* d_ws, size_t ws_size,
                              hipStream_t stream) {
    const float* x   = (const float*)d_in[0];
    const int*   ei  = (const int*)d_in[1];
    const int*   row = ei;
    const int*   col = ei + N_EDGES;
    const int*   bat = (const int*)d_in[2];
    const float* W1  = (const float*)d_in[4];
    const float* b1  = (const float*)d_in[5];
    const float* W2  = (const float*)d_in[6];
    const float* b2  = (const float*)d_in[7];
    const float* w3  = (const float*)d_in[8];
    const float* b3  = (const float*)d_in[9];
    const float* w4  = (const float*)d_in[10];
    const float* b4  = (const float*)d_in[11];
    const float* fw1 = (const float*)d_in[12];
    const float* fb1 = (const float*)d_in[13];
    const float* fw2 = (const float*)d_in[14];
    const float* fb2 = (const float*)d_in[15];

    char* wsb = (char*)d_ws;
    unsigned short* xws = (unsigned short*)wsb;       wsb += (size_t)(N_NODES + 1) * H1C * 2; // 12.8 MB (+zero row)
    float* x1     = (float*)wsb;                      wsb += (size_t)N_NODES * H1C * 4;       // 25.6 MB
    int*   erow   = (int*)wsb;                        wsb += (size_t)NBKT * BSTRIDE * 4;      // 16.0 MB
    // ebkt aliases x1 (16.0 MB <= 25.6 MB): consumed by k_csrw before k_agg1m writes x1
    unsigned int* ebkt = (unsigned int*)x1;
    int*   gcur   = (int*)wsb;                        wsb += (size_t)NBKT * 4;
    int2*  rowse  = (int2*)wsb;                       wsb += (size_t)N_NODES * 8;
    float* dis    = (float*)wsb;                      wsb += (size_t)N_NODES * 4;
    float* xws2   = (float*)wsb;                      wsb += (size_t)N_NODES * 4;
    int*   gstart = (int*)wsb;                        wsb += (size_t)(B_GRAPHS + 1) * 4;
    float* outp   = (float*)d_out;

    hipMemsetAsync(gcur, 0, (size_t)NBKT * 4, stream);

    k_mscatter<<<(N_EDGES + MS_EPB - 1) / MS_EPB, 256, 0, stream>>>(row, col, gcur, ebkt);
    k_csrw<<<NBKT, 256, 0, stream>>>(ebkt, gcur, bat, x, W1, dis, rowse, erow, gstart, xws);
    k_agg1m<<<N_NODES / 4, 256, 0, stream>>>(rowse, erow, xws, dis, b1, W2, x1, xws2);
    k_poolhead<<<B_GRAPHS, 1024, 0, stream>>>(gstart, x1, rowse, erow, xws2, dis, b2,
                                              w3, b3, w4, b4, fw1, fb1, fw2, fb2, outp);
}

// Round 14
// 299.594 us; speedup vs baseline: 1.0287x; 1.0287x over previous
//
#include <hip/hip_runtime.h>
#include <math.h>

#define N_NODES 100000
#define N_EDGES 3200000
#define B_GRAPHS 500
#define K_TOP 30
#define F_INN 128
#define H1C 64
#define NUM_CLASSES 18
#define XC 65               // H1 + 1
#define P_LEN (K_TOP * XC)  // 1950
#define C3_OUT 16
#define C3_K 97
#define C3_L 20
#define P2_L 10
#define C4_OUT 32
#define C4_K 5
#define C4_L 6
#define FC1_IN 192
#define FC1_OUT 128

#define BK_SHIFT 7
#define BK_NODES 128                               // nodes per bucket
#define NBKT ((N_NODES + BK_NODES - 1) / BK_NODES) // 782
#define BSTRIDE 5120                               // slots per bucket (mean 4096 + 16 sigma)
#define MS_EPT 64                                  // edges per thread in mscatter
#define MS_EPB (256 * MS_EPT)                      // 16384 edges per block -> 196 blocks

#define REG_B 544                                  // bytes per (t,h) LDS region (512 + 32 skew)

typedef __attribute__((ext_vector_type(8))) short bf16x8;
typedef __attribute__((ext_vector_type(4))) float f32x4;
typedef __attribute__((ext_vector_type(2))) unsigned int u32x2;

// bf16 helpers
static __device__ __forceinline__ unsigned short f2bf(float f) {
    unsigned int u = __float_as_uint(f);
    u += 0x7FFFu + ((u >> 16) & 1u);   // round to nearest even
    return (unsigned short)(u >> 16);
}

// ------- multi-split scatter: ebkt[b*BSTRIDE + slot] = (row<<7 | col_local) -------
__global__ __launch_bounds__(256) void k_mscatter(const int* __restrict__ row,
                                                  const int* __restrict__ col,
                                                  int* __restrict__ gcur,
                                                  unsigned int* __restrict__ ebkt) {
    __shared__ int hist[NBKT];
    __shared__ int base[NBKT];
    int tid = threadIdx.x;
    for (int i = tid; i < NBKT; i += 256) hist[i] = 0;
    __syncthreads();
    unsigned int pk[MS_EPT];   // (bucket<<12) | rank, or sentinel
    unsigned int pay[MS_EPT];  // (row<<7) | col_local
    int e0q = blockIdx.x * (MS_EPB / 4);   // int4 index base
#pragma unroll
    for (int j = 0; j < MS_EPT / 4; ++j) {
        int q = e0q + j * 256 + tid;
        bool ok = (q * 4) < N_EDGES;       // N_EDGES % 4 == 0: all-or-nothing
        int4 r4 = ok ? ((const int4*)row)[q] : make_int4(0, 0, 0, 0);
        int4 c4 = ok ? ((const int4*)col)[q] : make_int4(0, 0, 0, 0);
#pragma unroll
        for (int k = 0; k < 4; ++k) {
            int jj = j * 4 + k;
            pk[jj] = 0xFFFFFFFFu;
            int r = k == 0 ? r4.x : k == 1 ? r4.y : k == 2 ? r4.z : r4.w;
            int c = k == 0 ? c4.x : k == 1 ? c4.y : k == 2 ? c4.z : c4.w;
            if (ok && r != c) {
                int b = c >> BK_SHIFT;
                int rank = atomicAdd(&hist[b], 1);
                pk[jj] = ((unsigned int)b << 12) | (unsigned int)rank;   // rank < 4096 (mean 21)
                pay[jj] = ((unsigned int)r << BK_SHIFT) | (unsigned int)(c & (BK_NODES - 1));
            }
        }
    }
    __syncthreads();
    for (int i = tid; i < NBKT; i += 256)
        base[i] = hist[i] ? (i * BSTRIDE + atomicAdd(&gcur[i], hist[i])) : 0;
    __syncthreads();
#pragma unroll
    for (int j = 0; j < MS_EPT; ++j) {
        if (pk[j] != 0xFFFFFFFFu) {
            int b = pk[j] >> 12;
            int rank = pk[j] & 0xFFF;
            ebkt[base[b] + rank] = pay[j];
        }
    }
}

// ------- merged CSR build + gstart table + xw1 MFMA (block-local fusion) -------
__global__ __launch_bounds__(256) void k_csrw(const unsigned int* __restrict__ ebkt,
                                              const int* __restrict__ gcur,
                                              const int* __restrict__ batch,
                                              const float* __restrict__ x,
                                              const float* __restrict__ W1,
                                              float* __restrict__ dis,
                                              int2* __restrict__ rowse,
                                              int* __restrict__ erow,
                                              int* __restrict__ gstart,
                                              unsigned short* __restrict__ xw) {
    __shared__ __align__(16) char ubuf[BSTRIDE * 4];   // 20480B: ebs, then w1s
    __shared__ int cnt[BK_NODES];
    __shared__ int s[256];
    __shared__ int cur[BK_NODES];
    __shared__ float diss[BK_NODES];
    int b = blockIdx.x, t = threadIdx.x;
    unsigned int* ebs = (unsigned int*)ubuf;
    if (t < BK_NODES) {
        cnt[t] = 0;
        int node = b * BK_NODES + t;
        if (node < N_NODES) {   // graph boundary marking (disjoint writes across blocks)
            int bc = batch[node];
            int bp = node ? batch[node - 1] : -1;
            for (int g = bp + 1; g <= bc; ++g) gstart[g] = node;
            if (node == N_NODES - 1)
                for (int g = bc + 1; g <= B_GRAPHS; ++g) gstart[g] = N_NODES;
        }
    }
    __syncthreads();
    int n = gcur[b];
    int lo = b * BSTRIDE;
    for (int i = t; i < n; i += 256) {
        unsigned int pk = ebkt[lo + i];
        ebs[i] = pk;
        atomicAdd(&cnt[pk & (BK_NODES - 1)], 1);
    }
    __syncthreads();
    int v = (t < BK_NODES) ? cnt[t] : 0;
    s[t] = v;
    __syncthreads();
    for (int off = 1; off < BK_NODES; off <<= 1) {
        int add = (t >= off) ? s[t - off] : 0;
        __syncthreads();
        s[t] += add;
        __syncthreads();
    }
    int ex = s[t] - v;
    if (t < BK_NODES) {
        float dv = rsqrtf((float)v + 1.0f);
        diss[t] = dv;
        int node = b * BK_NODES + t;
        if (node < N_NODES) {
            dis[node] = dv;
            rowse[node] = make_int2(lo + ex, lo + ex + v);
        }
        cur[t] = lo + ex;
    }
    __syncthreads();
    for (int i = t; i < n; i += 256) {
        unsigned int pk = ebs[i];
        int cl = pk & (BK_NODES - 1);
        int slot = atomicAdd(&cur[cl], 1);
        erow[slot] = (int)((pk >> BK_SHIFT) << 7);   // byte offset into bf16 rows (128B)
    }
    __syncthreads();   // ebs dead: safe to overwrite with w1s
    // ---- xw1 phase: xws rows for this block's 128 nodes ----
    unsigned short* w1s = (unsigned short*)ubuf;   // 16KB
    if (b == 0 && t < 32)
        ((unsigned int*)(xw + (size_t)N_NODES * H1C))[t] = 0;   // zero pad row
    for (int idx = t; idx < 16 * 64 * 8; idx += 256) {
        int f = idx >> 9;
        int l = (idx >> 3) & 63;
        int j = idx & 7;
        int kq = f >> 2, t4 = f & 3;
        int k = kq * 32 + ((l >> 4) << 3) + j;
        int nn = t4 * 16 + (l & 15);
        w1s[idx] = f2bf(W1[k * H1C + nn]);
    }
    __syncthreads();
    int wave = t >> 6;
    int lane = t & 63;
    int quad = lane >> 4;
    int m = lane & 15;

    bf16x8 bw[16];
#pragma unroll
    for (int f = 0; f < 16; ++f)
        bw[f] = *(const bf16x8*)&w1s[(f * 64 + lane) * 8];

#pragma unroll
    for (int rt = 0; rt < 2; ++rt) {
        int wrow0 = b * BK_NODES + rt * 64 + wave * 16;
        f32x4 acc[4];
#pragma unroll
        for (int tt = 0; tt < 4; ++tt) acc[tt] = (f32x4){0.f, 0.f, 0.f, 0.f};

        int rowA = wrow0 + m;
        size_t ra = (size_t)(rowA < N_NODES ? rowA : N_NODES - 1);
#pragma unroll
        for (int kq = 0; kq < 4; ++kq) {
            const float* xp = x + ra * F_INN + kq * 32 + quad * 8;
            float4 f0 = ((const float4*)xp)[0];
            float4 f1 = ((const float4*)xp)[1];
            bf16x8 a;
            a[0] = (short)f2bf(f0.x); a[1] = (short)f2bf(f0.y);
            a[2] = (short)f2bf(f0.z); a[3] = (short)f2bf(f0.w);
            a[4] = (short)f2bf(f1.x); a[5] = (short)f2bf(f1.y);
            a[6] = (short)f2bf(f1.z); a[7] = (short)f2bf(f1.w);
#pragma unroll
            for (int tt = 0; tt < 4; ++tt)
                acc[tt] = __builtin_amdgcn_mfma_f32_16x16x32_bf16(a, bw[kq * 4 + tt], acc[tt], 0, 0, 0);
        }
#pragma unroll
        for (int r = 0; r < 4; ++r) {
            int rowD = wrow0 + quad * 4 + r;
            if (rowD < N_NODES) {
                float dsc = diss[rowD - b * BK_NODES];
#pragma unroll
                for (int tt = 0; tt < 4; ++tt)
                    xw[(size_t)rowD * H1C + tt * 16 + m] = f2bf(acc[tt][r] * dsc);
            }
        }
    }
}

// ------- conv1 gather via MFMA aggregation (R7-proven non-pipelined form) -------
__global__ __launch_bounds__(256) void k_agg1m(const int2* __restrict__ rowse,
                                               const int* __restrict__ erow,
                                               const unsigned short* __restrict__ xws,
                                               const float* __restrict__ dis,
                                               const float* __restrict__ b1,
                                               const float* __restrict__ W2,
                                               float* __restrict__ x1,
                                               float* __restrict__ xws2) {
    __shared__ __align__(16) char slds[4][8 * REG_B];   // 17408 B
    int tid = threadIdx.x;
    int wave = tid >> 6;
    int lane = tid & 63;
    int wid = blockIdx.x * 4 + wave;   // wid < N_NODES always (exact grid)
    int grp = lane >> 3;   // 0..7  -> edge-within-octet
    int sub = lane & 7;    // 0..7  -> 16B chunk of the 128B row
    int2 se = rowse[wid];
    int base = se.x, endp = se.y;
    int nE = endp - base;
    const char* xb = (const char*)xws;
    const int ZR = N_NODES << 7;   // zero row pad (L1-cached)

    char* wreg = &slds[wave][0];
    char* dst0 = wreg + ((sub >> 1) * 2 + ((grp >> 2) & 1)) * REG_B + (grp & 3) * 32 + (sub & 1) * 16;
    unsigned int trb = (unsigned int)(size_t)wreg +
                       (unsigned int)(((lane >> 4) * 64 + (lane & 15)) * 2);

    bf16x8 aones;
#pragma unroll
    for (int i = 0; i < 8; ++i) aones[i] = (short)0x3F80;   // bf16 1.0

    f32x4 ac0 = (f32x4){0.f, 0.f, 0.f, 0.f};
    f32x4 ac1 = ac0, ac2 = ac0, ac3 = ac0;

    for (int w0 = 0; w0 < nE; w0 += 64) {
        int idx = base + w0 + lane;
        int myoff = (idx < endp) ? erow[idx] : ZR;
#pragma unroll
        for (int hf = 0; hf < 2; ++hf) {
            if (w0 + hf * 32 < nE) {   // wave-uniform
#pragma unroll
                for (int ii = 0; ii < 4; ++ii) {
                    int o = __shfl(myoff, hf * 32 + ii * 8 + grp);
                    uint4 v = ((const uint4*)(xb + o))[sub];
                    *(uint4*)(dst0 + ii * 128) = v;
                }
                asm volatile("s_waitcnt lgkmcnt(0)" ::: "memory");
                __builtin_amdgcn_sched_barrier(0);
                u32x2 q0, q1, q2, q3, q4, q5, q6, q7;
                asm volatile("ds_read_b64_tr_b16 %0, %1 offset:0"    : "=v"(q0) : "v"(trb) : "memory");
                asm volatile("ds_read_b64_tr_b16 %0, %1 offset:544"  : "=v"(q1) : "v"(trb) : "memory");
                asm volatile("ds_read_b64_tr_b16 %0, %1 offset:1088" : "=v"(q2) : "v"(trb) : "memory");
                asm volatile("ds_read_b64_tr_b16 %0, %1 offset:1632" : "=v"(q3) : "v"(trb) : "memory");
                asm volatile("ds_read_b64_tr_b16 %0, %1 offset:2176" : "=v"(q4) : "v"(trb) : "memory");
                asm volatile("ds_read_b64_tr_b16 %0, %1 offset:2720" : "=v"(q5) : "v"(trb) : "memory");
                asm volatile("ds_read_b64_tr_b16 %0, %1 offset:3264" : "=v"(q6) : "v"(trb) : "memory");
                asm volatile("ds_read_b64_tr_b16 %0, %1 offset:3808" : "=v"(q7) : "v"(trb) : "memory");
                asm volatile("s_waitcnt lgkmcnt(0)" ::: "memory");
                __builtin_amdgcn_sched_barrier(0);
                union FU { bf16x8 f; unsigned int d[4]; };
                FU f0, f1, f2, f3;
                f0.d[0] = q0.x; f0.d[1] = q0.y; f0.d[2] = q1.x; f0.d[3] = q1.y;
                f1.d[0] = q2.x; f1.d[1] = q2.y; f1.d[2] = q3.x; f1.d[3] = q3.y;
                f2.d[0] = q4.x; f2.d[1] = q4.y; f2.d[2] = q5.x; f2.d[3] = q5.y;
                f3.d[0] = q6.x; f3.d[1] = q6.y; f3.d[2] = q7.x; f3.d[3] = q7.y;
                ac0 = __builtin_amdgcn_mfma_f32_16x16x32_bf16(aones, f0.f, ac0, 0, 0, 0);
                ac1 = __builtin_amdgcn_mfma_f32_16x16x32_bf16(aones, f1.f, ac1, 0, 0, 0);
                ac2 = __builtin_amdgcn_mfma_f32_16x16x32_bf16(aones, f2.f, ac2, 0, 0, 0);
                ac3 = __builtin_amdgcn_mfma_f32_16x16x32_bf16(aones, f3.f, ac3, 0, 0, 0);
            }
        }
    }
    float v0s = __shfl(ac0[0], lane & 15);
    float v1s = __shfl(ac1[0], lane & 15);
    float v2s = __shfl(ac2[0], lane & 15);
    float v3s = __shfl(ac3[0], lane & 15);
    int ts = lane >> 4;
    float aggv = ts == 0 ? v0s : (ts == 1 ? v1s : (ts == 2 ? v2s : v3s));
    float d = dis[wid];
    unsigned int su = xws[(size_t)wid * H1C + lane];   // self row (pre-scaled by dis[wid])
    float self = __uint_as_float(su << 16);
    float v = tanhf(d * (aggv + self) + b1[lane]);
    x1[(size_t)wid * H1C + lane] = v;
    float s = v * W2[lane];
#pragma unroll
    for (int off = 1; off < 64; off <<= 1) s += __shfl_xor(s, off);
    if (lane == 0) xws2[wid] = d * s;   // pre-scaled by dis
}

// ------- fused conv2 + sort-pool + head: one block per graph (256 threads, R12 form) -------
// conv2: dual-node MLP — each 8-lane group walks TWO nodes in lockstep so two
// independent erow/xws2 gathers are in flight per lane (halves serial passes).
__global__ __launch_bounds__(256) void k_poolhead(const int* __restrict__ gstart,
                                                  const float* __restrict__ x1,
                                                  const int2* __restrict__ rowse,
                                                  const int* __restrict__ erow,
                                                  const float* __restrict__ xws2,
                                                  const float* __restrict__ dis,
                                                  const float* __restrict__ b2,
                                                  const float* __restrict__ w3, const float* __restrict__ b3,
                                                  const float* __restrict__ w4, const float* __restrict__ b4,
                                                  const float* __restrict__ fw1, const float* __restrict__ fb1,
                                                  const float* __restrict__ fw2, const float* __restrict__ fb2,
                                                  float* __restrict__ out) {
    __shared__ float x2s[512];
    __shared__ int sel[K_TOP];
    __shared__ float ps[P_LEN];
    __shared__ float h1s[C3_OUT * C3_L];
    __shared__ float h2s[C3_OUT * P2_L];
    __shared__ float h3s[FC1_IN];
    __shared__ float lls[FC1_OUT];
    __shared__ float outs[NUM_CLASSES];
    int g = blockIdx.x, tid = threadIdx.x;
    int start = gstart[g];
    int end = gstart[g + 1];
    int count = end - start;
    if (count > 512) count = 512;
    int wave = tid >> 6, lane = tid & 63;
    // conv2: 4 waves x 8 groups; each group handles nodes li and li+32 together
    {
        float b2v = b2[0];
        int grp8 = lane >> 3, sub8 = lane & 7;
        for (int t0 = 0; t0 < count; t0 += 64) {
            int liA = t0 + wave * 8 + grp8;
            int liB = liA + 32;
            int nodeA = start + liA, nodeB = start + liB;
            bool okA = liA < count, okB = liB < count;
            int2 seA = okA ? rowse[nodeA] : make_int2(0, 0);
            int2 seB = okB ? rowse[nodeB] : make_int2(0, 0);
            float accA = 0.f, accB = 0.f;
            int iA = seA.x + sub8, iB = seB.x + sub8;
            while (iA < seA.y && iB < seB.y) {   // two independent gathers in flight
                int oA = erow[iA];
                int oB = erow[iB];
                accA += xws2[oA >> 7];
                accB += xws2[oB >> 7];
                iA += 8; iB += 8;
            }
            while (iA < seA.y) { accA += xws2[erow[iA] >> 7]; iA += 8; }
            while (iB < seB.y) { accB += xws2[erow[iB] >> 7]; iB += 8; }
            accA += __shfl_xor(accA, 1);
            accA += __shfl_xor(accA, 2);
            accA += __shfl_xor(accA, 4);
            accB += __shfl_xor(accB, 1);
            accB += __shfl_xor(accB, 2);
            accB += __shfl_xor(accB, 4);
            if (okA && sub8 == 0) x2s[liA] = tanhf(dis[nodeA] * (accA + xws2[nodeA]) + b2v);
            if (okB && sub8 == 0) x2s[liB] = tanhf(dis[nodeB] * (accB + xws2[nodeB]) + b2v);
        }
    }
    __syncthreads();
    if (wave == 0) {
        unsigned long long k[8];
#pragma unroll
        for (int i = 0; i < 8; ++i) {
            int idx = i * 64 + lane;
            unsigned long long key = 0ULL;
            if (idx < count) {
                unsigned int bits = __float_as_uint(x2s[idx]);
                unsigned int u = (bits & 0x80000000u) ? ~bits : (bits | 0x80000000u);
                key = ((unsigned long long)u << 32) | (unsigned int)(~(unsigned int)(start + idx));
            }
            k[i] = key;
        }
        int kk = count < K_TOP ? count : K_TOP;
        for (int j = 0; j < kk; ++j) {
            unsigned long long best = k[0];
#pragma unroll
            for (int i = 1; i < 8; ++i) if (k[i] > best) best = k[i];
#pragma unroll
            for (int off = 32; off; off >>= 1) {
                unsigned long long o = __shfl_xor(best, off);
                if (o > best) best = o;
            }
            int node = (int)(~(unsigned int)(best & 0xFFFFFFFFULL));
#pragma unroll
            for (int i = 0; i < 8; ++i) if (k[i] == best) k[i] = 0ULL;
            if (lane == 0) sel[j] = node;
        }
        if (lane >= kk && lane < K_TOP) sel[lane] = -1;
    }
    __syncthreads();
    for (int t = tid; t < P_LEN; t += 256) {
        int j = t / XC, c = t - j * XC;
        int node = sel[j];
        float v = 0.0f;
        if (node >= 0) v = (c < H1C) ? x1[(size_t)node * H1C + c] : x2s[node - start];
        ps[t] = v;
    }
    __syncthreads();
    for (int o = tid; o < C3_OUT * C3_L; o += 256) {
        int oc = o / C3_L, pos = o % C3_L;
        float s = b3[oc];
        const float* w = w3 + oc * C3_K;
        int base = pos * C3_K;
        for (int k = 0; k < C3_K; ++k) s += ps[base + k] * w[k];
        h1s[o] = fmaxf(s, 0.0f);
    }
    __syncthreads();
    if (tid < C3_OUT * P2_L) {
        int oc = tid / P2_L, pos = tid % P2_L;
        h2s[tid] = fmaxf(h1s[oc * C3_L + 2 * pos], h1s[oc * C3_L + 2 * pos + 1]);
    }
    __syncthreads();
    if (tid < C4_OUT * C4_L) {
        int oc = tid / C4_L, pos = tid % C4_L;
        float s = b4[oc];
        for (int ic = 0; ic < C3_OUT; ++ic)
#pragma unroll
            for (int k = 0; k < C4_K; ++k)
                s += h2s[ic * P2_L + pos + k] * w4[oc * C3_OUT * C4_K + ic * C4_K + k];
        h3s[oc * C4_L + pos] = fmaxf(s, 0.0f);
    }
    __syncthreads();
    if (tid < FC1_OUT) {
        float s = fb1[tid];
        for (int i = 0; i < FC1_IN; ++i) s += h3s[i] * fw1[i * FC1_OUT + tid];
        float v = fmaxf(s, 0.0f);
        lls[tid] = v;
        out[2 * B_GRAPHS * NUM_CLASSES + (size_t)g * FC1_OUT + tid] = v;
    }
    __syncthreads();
    if (tid < NUM_CLASSES) {
        float s = fb2[tid];
        for (int j = 0; j < FC1_OUT; ++j) s += lls[j] * fw2[j * NUM_CLASSES + tid];
        outs[tid] = s;
        out[B_GRAPHS * NUM_CLASSES + (size_t)g * NUM_CLASSES + tid] = s;
    }
    __syncthreads();
    if (tid < NUM_CLASSES) {
        float m = -INFINITY;
        for (int k2 = 0; k2 < NUM_CLASSES; ++k2) m = fmaxf(m, outs[k2]);
        float se = 0.0f;
        for (int k2 = 0; k2 < NUM_CLASSES; ++k2) se += expf(outs[k2] - m);
        out[(size_t)g * NUM_CLASSES + tid] = outs[tid] - m - logf(se);
    }
}

extern "C" void kernel_launch(void* const* d_in, const int* in_sizes, int n_in,
                              void* d_out, int out_size, void* d_ws, size_t ws_size,
                              hipStream_t stream) {
    const float* x   = (const float*)d_in[0];
    const int*   ei  = (const int*)d_in[1];
    const int*   row = ei;
    const int*   col = ei + N_EDGES;
    const int*   bat = (const int*)d_in[2];
    const float* W1  = (const float*)d_in[4];
    const float* b1  = (const float*)d_in[5];
    const float* W2  = (const float*)d_in[6];
    const float* b2  = (const float*)d_in[7];
    const float* w3  = (const float*)d_in[8];
    const float* b3  = (const float*)d_in[9];
    const float* w4  = (const float*)d_in[10];
    const float* b4  = (const float*)d_in[11];
    const float* fw1 = (const float*)d_in[12];
    const float* fb1 = (const float*)d_in[13];
    const float* fw2 = (const float*)d_in[14];
    const float* fb2 = (const float*)d_in[15];

    char* wsb = (char*)d_ws;
    unsigned short* xws = (unsigned short*)wsb;       wsb += (size_t)(N_NODES + 1) * H1C * 2; // 12.8 MB (+zero row)
    float* x1     = (float*)wsb;                      wsb += (size_t)N_NODES * H1C * 4;       // 25.6 MB
    int*   erow   = (int*)wsb;                        wsb += (size_t)NBKT * BSTRIDE * 4;      // 16.0 MB
    // ebkt aliases x1 (16.0 MB <= 25.6 MB): consumed by k_csrw before k_agg1m writes x1
    unsigned int* ebkt = (unsigned int*)x1;
    int*   gcur   = (int*)wsb;                        wsb += (size_t)NBKT * 4;
    int2*  rowse  = (int2*)wsb;                       wsb += (size_t)N_NODES * 8;
    float* dis    = (float*)wsb;                      wsb += (size_t)N_NODES * 4;
    float* xws2   = (float*)wsb;                      wsb += (size_t)N_NODES * 4;
    int*   gstart = (int*)wsb;                        wsb += (size_t)(B_GRAPHS + 1) * 4;
    float* outp   = (float*)d_out;

    hipMemsetAsync(gcur, 0, (size_t)NBKT * 4, stream);

    k_mscatter<<<(N_EDGES + MS_EPB - 1) / MS_EPB, 256, 0, stream>>>(row, col, gcur, ebkt);
    k_csrw<<<NBKT, 256, 0, stream>>>(ebkt, gcur, bat, x, W1, dis, rowse, erow, gstart, xws);
    k_agg1m<<<N_NODES / 4, 256, 0, stream>>>(rowse, erow, xws, dis, b1, W2, x1, xws2);
    k_poolhead<<<B_GRAPHS, 256, 0, stream>>>(gstart, x1, rowse, erow, xws2, dis, b2,
                                             w3, b3, w4, b4, fw1, fb1, fw2, fb2, outp);
}

// Round 15
// 298.811 us; speedup vs baseline: 1.0314x; 1.0026x over previous
//
#include <hip/hip_runtime.h>
#include <math.h>

#define N_NODES 100000
#define N_EDGES 3200000
#define B_GRAPHS 500
#define K_TOP 30
#define F_INN 128
#define H1C 64
#define NUM_CLASSES 18
#define XC 65               // H1 + 1
#define P_LEN (K_TOP * XC)  // 1950
#define C3_OUT 16
#define C3_K 97
#define C3_L 20
#define P2_L 10
#define C4_OUT 32
#define C4_K 5
#define C4_L 6
#define FC1_IN 192
#define FC1_OUT 128

#define BK_SHIFT 7
#define BK_NODES 128                               // nodes per bucket
#define NBKT ((N_NODES + BK_NODES - 1) / BK_NODES) // 782
#define BSTRIDE 5120                               // slots per bucket (mean 4096 + 16 sigma)
#define MS_EPT 64                                  // edges per thread in mscatter
#define MS_EPB (256 * MS_EPT)                      // 16384 edges per block -> 196 blocks

#define REG_B 544                                  // bytes per (t,h) LDS region (512 + 32 skew)

typedef __attribute__((ext_vector_type(8))) short bf16x8;
typedef __attribute__((ext_vector_type(4))) float f32x4;
typedef __attribute__((ext_vector_type(2))) unsigned int u32x2;

// bf16 helpers
static __device__ __forceinline__ unsigned short f2bf(float f) {
    unsigned int u = __float_as_uint(f);
    u += 0x7FFFu + ((u >> 16) & 1u);   // round to nearest even
    return (unsigned short)(u >> 16);
}

// ------- multi-split scatter: ebkt[b*BSTRIDE + slot] = (row<<7 | col_local) -------
__global__ __launch_bounds__(256) void k_mscatter(const int* __restrict__ row,
                                                  const int* __restrict__ col,
                                                  int* __restrict__ gcur,
                                                  unsigned int* __restrict__ ebkt) {
    __shared__ int hist[NBKT];
    __shared__ int base[NBKT];
    int tid = threadIdx.x;
    for (int i = tid; i < NBKT; i += 256) hist[i] = 0;
    __syncthreads();
    unsigned int pk[MS_EPT];   // (bucket<<12) | rank, or sentinel
    unsigned int pay[MS_EPT];  // (row<<7) | col_local
    int e0q = blockIdx.x * (MS_EPB / 4);   // int4 index base
#pragma unroll
    for (int j = 0; j < MS_EPT / 4; ++j) {
        int q = e0q + j * 256 + tid;
        bool ok = (q * 4) < N_EDGES;       // N_EDGES % 4 == 0: all-or-nothing
        int4 r4 = ok ? ((const int4*)row)[q] : make_int4(0, 0, 0, 0);
        int4 c4 = ok ? ((const int4*)col)[q] : make_int4(0, 0, 0, 0);
#pragma unroll
        for (int k = 0; k < 4; ++k) {
            int jj = j * 4 + k;
            pk[jj] = 0xFFFFFFFFu;
            int r = k == 0 ? r4.x : k == 1 ? r4.y : k == 2 ? r4.z : r4.w;
            int c = k == 0 ? c4.x : k == 1 ? c4.y : k == 2 ? c4.z : c4.w;
            if (ok && r != c) {
                int b = c >> BK_SHIFT;
                int rank = atomicAdd(&hist[b], 1);
                pk[jj] = ((unsigned int)b << 12) | (unsigned int)rank;   // rank < 4096 (mean 21)
                pay[jj] = ((unsigned int)r << BK_SHIFT) | (unsigned int)(c & (BK_NODES - 1));
            }
        }
    }
    __syncthreads();
    for (int i = tid; i < NBKT; i += 256)
        base[i] = hist[i] ? (i * BSTRIDE + atomicAdd(&gcur[i], hist[i])) : 0;
    __syncthreads();
#pragma unroll
    for (int j = 0; j < MS_EPT; ++j) {
        if (pk[j] != 0xFFFFFFFFu) {
            int b = pk[j] >> 12;
            int rank = pk[j] & 0xFFF;
            ebkt[base[b] + rank] = pay[j];
        }
    }
}

// ------- merged CSR build + gstart table + xw1 MFMA (block-local fusion) -------
__global__ __launch_bounds__(256) void k_csrw(const unsigned int* __restrict__ ebkt,
                                              const int* __restrict__ gcur,
                                              const int* __restrict__ batch,
                                              const float* __restrict__ x,
                                              const float* __restrict__ W1,
                                              float* __restrict__ dis,
                                              int2* __restrict__ rowse,
                                              int* __restrict__ erow,
                                              int* __restrict__ gstart,
                                              unsigned short* __restrict__ xw) {
    __shared__ __align__(16) char ubuf[BSTRIDE * 4];   // 20480B: ebs, then w1s
    __shared__ int cnt[BK_NODES];
    __shared__ int s[256];
    __shared__ int cur[BK_NODES];
    __shared__ float diss[BK_NODES];
    int b = blockIdx.x, t = threadIdx.x;
    unsigned int* ebs = (unsigned int*)ubuf;
    if (t < BK_NODES) {
        cnt[t] = 0;
        int node = b * BK_NODES + t;
        if (node < N_NODES) {   // graph boundary marking (disjoint writes across blocks)
            int bc = batch[node];
            int bp = node ? batch[node - 1] : -1;
            for (int g = bp + 1; g <= bc; ++g) gstart[g] = node;
            if (node == N_NODES - 1)
                for (int g = bc + 1; g <= B_GRAPHS; ++g) gstart[g] = N_NODES;
        }
    }
    __syncthreads();
    int n = gcur[b];
    int lo = b * BSTRIDE;
    for (int i = t; i < n; i += 256) {
        unsigned int pk = ebkt[lo + i];
        ebs[i] = pk;
        atomicAdd(&cnt[pk & (BK_NODES - 1)], 1);
    }
    __syncthreads();
    int v = (t < BK_NODES) ? cnt[t] : 0;
    s[t] = v;
    __syncthreads();
    for (int off = 1; off < BK_NODES; off <<= 1) {
        int add = (t >= off) ? s[t - off] : 0;
        __syncthreads();
        s[t] += add;
        __syncthreads();
    }
    int ex = s[t] - v;
    if (t < BK_NODES) {
        float dv = rsqrtf((float)v + 1.0f);
        diss[t] = dv;
        int node = b * BK_NODES + t;
        if (node < N_NODES) {
            dis[node] = dv;
            rowse[node] = make_int2(lo + ex, lo + ex + v);
        }
        cur[t] = lo + ex;
    }
    __syncthreads();
    for (int i = t; i < n; i += 256) {
        unsigned int pk = ebs[i];
        int cl = pk & (BK_NODES - 1);
        int slot = atomicAdd(&cur[cl], 1);
        erow[slot] = (int)((pk >> BK_SHIFT) << 7);   // byte offset into bf16 rows (128B)
    }
    __syncthreads();   // ebs dead: safe to overwrite with w1s
    // ---- xw1 phase: xws rows for this block's 128 nodes ----
    unsigned short* w1s = (unsigned short*)ubuf;   // 16KB
    if (b == 0 && t < 32)
        ((unsigned int*)(xw + (size_t)N_NODES * H1C))[t] = 0;   // zero pad row
    for (int idx = t; idx < 16 * 64 * 8; idx += 256) {
        int f = idx >> 9;
        int l = (idx >> 3) & 63;
        int j = idx & 7;
        int kq = f >> 2, t4 = f & 3;
        int k = kq * 32 + ((l >> 4) << 3) + j;
        int nn = t4 * 16 + (l & 15);
        w1s[idx] = f2bf(W1[k * H1C + nn]);
    }
    __syncthreads();
    int wave = t >> 6;
    int lane = t & 63;
    int quad = lane >> 4;
    int m = lane & 15;

    bf16x8 bw[16];
#pragma unroll
    for (int f = 0; f < 16; ++f)
        bw[f] = *(const bf16x8*)&w1s[(f * 64 + lane) * 8];

#pragma unroll
    for (int rt = 0; rt < 2; ++rt) {
        int wrow0 = b * BK_NODES + rt * 64 + wave * 16;
        f32x4 acc[4];
#pragma unroll
        for (int tt = 0; tt < 4; ++tt) acc[tt] = (f32x4){0.f, 0.f, 0.f, 0.f};

        int rowA = wrow0 + m;
        size_t ra = (size_t)(rowA < N_NODES ? rowA : N_NODES - 1);
#pragma unroll
        for (int kq = 0; kq < 4; ++kq) {
            const float* xp = x + ra * F_INN + kq * 32 + quad * 8;
            float4 f0 = ((const float4*)xp)[0];
            float4 f1 = ((const float4*)xp)[1];
            bf16x8 a;
            a[0] = (short)f2bf(f0.x); a[1] = (short)f2bf(f0.y);
            a[2] = (short)f2bf(f0.z); a[3] = (short)f2bf(f0.w);
            a[4] = (short)f2bf(f1.x); a[5] = (short)f2bf(f1.y);
            a[6] = (short)f2bf(f1.z); a[7] = (short)f2bf(f1.w);
#pragma unroll
            for (int tt = 0; tt < 4; ++tt)
                acc[tt] = __builtin_amdgcn_mfma_f32_16x16x32_bf16(a, bw[kq * 4 + tt], acc[tt], 0, 0, 0);
        }
#pragma unroll
        for (int r = 0; r < 4; ++r) {
            int rowD = wrow0 + quad * 4 + r;
            if (rowD < N_NODES) {
                float dsc = diss[rowD - b * BK_NODES];
#pragma unroll
                for (int tt = 0; tt < 4; ++tt)
                    xw[(size_t)rowD * H1C + tt * 16 + m] = f2bf(acc[tt][r] * dsc);
            }
        }
    }
}

// ------- conv1 gather via MFMA aggregation (R7-proven non-pipelined form) -------
__global__ __launch_bounds__(256) void k_agg1m(const int2* __restrict__ rowse,
                                               const int* __restrict__ erow,
                                               const unsigned short* __restrict__ xws,
                                               const float* __restrict__ dis,
                                               const float* __restrict__ b1,
                                               const float* __restrict__ W2,
                                               float* __restrict__ x1,
                                               float* __restrict__ xws2) {
    __shared__ __align__(16) char slds[4][8 * REG_B];   // 17408 B
    int tid = threadIdx.x;
    int wave = tid >> 6;
    int lane = tid & 63;
    int wid = blockIdx.x * 4 + wave;   // wid < N_NODES always (exact grid)
    int grp = lane >> 3;   // 0..7  -> edge-within-octet
    int sub = lane & 7;    // 0..7  -> 16B chunk of the 128B row
    int2 se = rowse[wid];
    int base = se.x, endp = se.y;
    int nE = endp - base;
    const char* xb = (const char*)xws;
    const int ZR = N_NODES << 7;   // zero row pad (L1-cached)

    char* wreg = &slds[wave][0];
    char* dst0 = wreg + ((sub >> 1) * 2 + ((grp >> 2) & 1)) * REG_B + (grp & 3) * 32 + (sub & 1) * 16;
    unsigned int trb = (unsigned int)(size_t)wreg +
                       (unsigned int)(((lane >> 4) * 64 + (lane & 15)) * 2);

    bf16x8 aones;
#pragma unroll
    for (int i = 0; i < 8; ++i) aones[i] = (short)0x3F80;   // bf16 1.0

    f32x4 ac0 = (f32x4){0.f, 0.f, 0.f, 0.f};
    f32x4 ac1 = ac0, ac2 = ac0, ac3 = ac0;

    for (int w0 = 0; w0 < nE; w0 += 64) {
        int idx = base + w0 + lane;
        int myoff = (idx < endp) ? erow[idx] : ZR;
#pragma unroll
        for (int hf = 0; hf < 2; ++hf) {
            if (w0 + hf * 32 < nE) {   // wave-uniform
#pragma unroll
                for (int ii = 0; ii < 4; ++ii) {
                    int o = __shfl(myoff, hf * 32 + ii * 8 + grp);
                    uint4 v = ((const uint4*)(xb + o))[sub];
                    *(uint4*)(dst0 + ii * 128) = v;
                }
                asm volatile("s_waitcnt lgkmcnt(0)" ::: "memory");
                __builtin_amdgcn_sched_barrier(0);
                u32x2 q0, q1, q2, q3, q4, q5, q6, q7;
                asm volatile("ds_read_b64_tr_b16 %0, %1 offset:0"    : "=v"(q0) : "v"(trb) : "memory");
                asm volatile("ds_read_b64_tr_b16 %0, %1 offset:544"  : "=v"(q1) : "v"(trb) : "memory");
                asm volatile("ds_read_b64_tr_b16 %0, %1 offset:1088" : "=v"(q2) : "v"(trb) : "memory");
                asm volatile("ds_read_b64_tr_b16 %0, %1 offset:1632" : "=v"(q3) : "v"(trb) : "memory");
                asm volatile("ds_read_b64_tr_b16 %0, %1 offset:2176" : "=v"(q4) : "v"(trb) : "memory");
                asm volatile("ds_read_b64_tr_b16 %0, %1 offset:2720" : "=v"(q5) : "v"(trb) : "memory");
                asm volatile("ds_read_b64_tr_b16 %0, %1 offset:3264" : "=v"(q6) : "v"(trb) : "memory");
                asm volatile("ds_read_b64_tr_b16 %0, %1 offset:3808" : "=v"(q7) : "v"(trb) : "memory");
                asm volatile("s_waitcnt lgkmcnt(0)" ::: "memory");
                __builtin_amdgcn_sched_barrier(0);
                union FU { bf16x8 f; unsigned int d[4]; };
                FU f0, f1, f2, f3;
                f0.d[0] = q0.x; f0.d[1] = q0.y; f0.d[2] = q1.x; f0.d[3] = q1.y;
                f1.d[0] = q2.x; f1.d[1] = q2.y; f1.d[2] = q3.x; f1.d[3] = q3.y;
                f2.d[0] = q4.x; f2.d[1] = q4.y; f2.d[2] = q5.x; f2.d[3] = q5.y;
                f3.d[0] = q6.x; f3.d[1] = q6.y; f3.d[2] = q7.x; f3.d[3] = q7.y;
                ac0 = __builtin_amdgcn_mfma_f32_16x16x32_bf16(aones, f0.f, ac0, 0, 0, 0);
                ac1 = __builtin_amdgcn_mfma_f32_16x16x32_bf16(aones, f1.f, ac1, 0, 0, 0);
                ac2 = __builtin_amdgcn_mfma_f32_16x16x32_bf16(aones, f2.f, ac2, 0, 0, 0);
                ac3 = __builtin_amdgcn_mfma_f32_16x16x32_bf16(aones, f3.f, ac3, 0, 0, 0);
            }
        }
    }
    float v0s = __shfl(ac0[0], lane & 15);
    float v1s = __shfl(ac1[0], lane & 15);
    float v2s = __shfl(ac2[0], lane & 15);
    float v3s = __shfl(ac3[0], lane & 15);
    int ts = lane >> 4;
    float aggv = ts == 0 ? v0s : (ts == 1 ? v1s : (ts == 2 ? v2s : v3s));
    float d = dis[wid];
    unsigned int su = xws[(size_t)wid * H1C + lane];   // self row (pre-scaled by dis[wid])
    float self = __uint_as_float(su << 16);
    float v = tanhf(d * (aggv + self) + b1[lane]);
    x1[(size_t)wid * H1C + lane] = v;
    float s = v * W2[lane];
#pragma unroll
    for (int off = 1; off < 64; off <<= 1) s += __shfl_xor(s, off);
    if (lane == 0) xws2[wid] = d * s;   // pre-scaled by dis
}

// ------- conv2: node-parallel, 8 nodes/wave, 8 lanes/node (R4-proven, high occupancy) -------
__global__ __launch_bounds__(256) void k_x2(const int2* __restrict__ rowse,
                                            const int* __restrict__ erow,
                                            const float* __restrict__ xws2,
                                            const float* __restrict__ dis,
                                            const float* __restrict__ b2,
                                            float* __restrict__ x2) {
    int lane = threadIdx.x & 63;
    int wglob = (blockIdx.x * 256 + threadIdx.x) >> 6;
    int grp = lane >> 3;   // node within wave
    int sub = lane & 7;    // edge lane within node
    int node = wglob * 8 + grp;   // < N_NODES always (exact grid)
    int2 se = rowse[node];
    float acc = 0.0f;
    for (int i = se.x + sub; i < se.y; i += 8)
        acc += xws2[erow[i] >> 7];
    acc += __shfl_xor(acc, 1);
    acc += __shfl_xor(acc, 2);
    acc += __shfl_xor(acc, 4);
    if (sub == 0)
        x2[node] = tanhf(dis[node] * (acc + xws2[node]) + b2[0]);
}

// ------- fused sort-pool + head: one block per graph (conv2 precomputed by k_x2) -------
__global__ __launch_bounds__(256) void k_poolhead(const int* __restrict__ gstart,
                                                  const float* __restrict__ x1,
                                                  const float* __restrict__ x2,
                                                  const float* __restrict__ w3, const float* __restrict__ b3,
                                                  const float* __restrict__ w4, const float* __restrict__ b4,
                                                  const float* __restrict__ fw1, const float* __restrict__ fb1,
                                                  const float* __restrict__ fw2, const float* __restrict__ fb2,
                                                  float* __restrict__ out) {
    __shared__ float x2s[512];
    __shared__ int sel[K_TOP];
    __shared__ float ps[P_LEN];
    __shared__ float h1s[C3_OUT * C3_L];
    __shared__ float h2s[C3_OUT * P2_L];
    __shared__ float h3s[FC1_IN];
    __shared__ float lls[FC1_OUT];
    __shared__ float outs[NUM_CLASSES];
    int g = blockIdx.x, tid = threadIdx.x;
    int start = gstart[g];
    int end = gstart[g + 1];
    int count = end - start;
    if (count > 512) count = 512;
    for (int t = tid; t < count; t += 256) x2s[t] = x2[start + t];
    __syncthreads();
    int wave = tid >> 6, lane = tid & 63;
    if (wave == 0) {
        unsigned long long k[8];
#pragma unroll
        for (int i = 0; i < 8; ++i) {
            int idx = i * 64 + lane;
            unsigned long long key = 0ULL;
            if (idx < count) {
                unsigned int bits = __float_as_uint(x2s[idx]);
                unsigned int u = (bits & 0x80000000u) ? ~bits : (bits | 0x80000000u);
                key = ((unsigned long long)u << 32) | (unsigned int)(~(unsigned int)(start + idx));
            }
            k[i] = key;
        }
        int kk = count < K_TOP ? count : K_TOP;
        for (int j = 0; j < kk; ++j) {
            unsigned long long best = k[0];
#pragma unroll
            for (int i = 1; i < 8; ++i) if (k[i] > best) best = k[i];
#pragma unroll
            for (int off = 32; off; off >>= 1) {
                unsigned long long o = __shfl_xor(best, off);
                if (o > best) best = o;
            }
            int node = (int)(~(unsigned int)(best & 0xFFFFFFFFULL));
#pragma unroll
            for (int i = 0; i < 8; ++i) if (k[i] == best) k[i] = 0ULL;
            if (lane == 0) sel[j] = node;
        }
        if (lane >= kk && lane < K_TOP) sel[lane] = -1;
    }
    __syncthreads();
    for (int t = tid; t < P_LEN; t += 256) {
        int j = t / XC, c = t - j * XC;
        int node = sel[j];
        float v = 0.0f;
        if (node >= 0) v = (c < H1C) ? x1[(size_t)node * H1C + c] : x2s[node - start];
        ps[t] = v;
    }
    __syncthreads();
    for (int o = tid; o < C3_OUT * C3_L; o += 256) {
        int oc = o / C3_L, pos = o % C3_L;
        float s = b3[oc];
        const float* w = w3 + oc * C3_K;
        int base = pos * C3_K;
        for (int k = 0; k < C3_K; ++k) s += ps[base + k] * w[k];
        h1s[o] = fmaxf(s, 0.0f);
    }
    __syncthreads();
    if (tid < C3_OUT * P2_L) {
        int oc = tid / P2_L, pos = tid % P2_L;
        h2s[tid] = fmaxf(h1s[oc * C3_L + 2 * pos], h1s[oc * C3_L + 2 * pos + 1]);
    }
    __syncthreads();
    if (tid < C4_OUT * C4_L) {
        int oc = tid / C4_L, pos = tid % C4_L;
        float s = b4[oc];
        for (int ic = 0; ic < C3_OUT; ++ic)
#pragma unroll
            for (int k = 0; k < C4_K; ++k)
                s += h2s[ic * P2_L + pos + k] * w4[oc * C3_OUT * C4_K + ic * C4_K + k];
        h3s[oc * C4_L + pos] = fmaxf(s, 0.0f);
    }
    __syncthreads();
    if (tid < FC1_OUT) {
        float s = fb1[tid];
        for (int i = 0; i < FC1_IN; ++i) s += h3s[i] * fw1[i * FC1_OUT + tid];
        float v = fmaxf(s, 0.0f);
        lls[tid] = v;
        out[2 * B_GRAPHS * NUM_CLASSES + (size_t)g * FC1_OUT + tid] = v;
    }
    __syncthreads();
    if (tid < NUM_CLASSES) {
        float s = fb2[tid];
        for (int j = 0; j < FC1_OUT; ++j) s += lls[j] * fw2[j * NUM_CLASSES + tid];
        outs[tid] = s;
        out[B_GRAPHS * NUM_CLASSES + (size_t)g * NUM_CLASSES + tid] = s;
    }
    __syncthreads();
    if (tid < NUM_CLASSES) {
        float m = -INFINITY;
        for (int k2 = 0; k2 < NUM_CLASSES; ++k2) m = fmaxf(m, outs[k2]);
        float se = 0.0f;
        for (int k2 = 0; k2 < NUM_CLASSES; ++k2) se += expf(outs[k2] - m);
        out[(size_t)g * NUM_CLASSES + tid] = outs[tid] - m - logf(se);
    }
}

extern "C" void kernel_launch(void* const* d_in, const int* in_sizes, int n_in,
                              void* d_out, int out_size, void* d_ws, size_t ws_size,
                              hipStream_t stream) {
    const float* x   = (const float*)d_in[0];
    const int*   ei  = (const int*)d_in[1];
    const int*   row = ei;
    const int*   col = ei + N_EDGES;
    const int*   bat = (const int*)d_in[2];
    const float* W1  = (const float*)d_in[4];
    const float* b1  = (const float*)d_in[5];
    const float* W2  = (const float*)d_in[6];
    const float* b2  = (const float*)d_in[7];
    const float* w3  = (const float*)d_in[8];
    const float* b3  = (const float*)d_in[9];
    const float* w4  = (const float*)d_in[10];
    const float* b4  = (const float*)d_in[11];
    const float* fw1 = (const float*)d_in[12];
    const float* fb1 = (const float*)d_in[13];
    const float* fw2 = (const float*)d_in[14];
    const float* fb2 = (const float*)d_in[15];

    char* wsb = (char*)d_ws;
    unsigned short* xws = (unsigned short*)wsb;       wsb += (size_t)(N_NODES + 1) * H1C * 2; // 12.8 MB (+zero row)
    float* x1     = (float*)wsb;                      wsb += (size_t)N_NODES * H1C * 4;       // 25.6 MB
    int*   erow   = (int*)wsb;                        wsb += (size_t)NBKT * BSTRIDE * 4;      // 16.0 MB
    // ebkt aliases x1 (16.0 MB <= 25.6 MB): consumed by k_csrw before k_agg1m writes x1
    unsigned int* ebkt = (unsigned int*)x1;
    int*   gcur   = (int*)wsb;                        wsb += (size_t)NBKT * 4;
    int2*  rowse  = (int2*)wsb;                       wsb += (size_t)N_NODES * 8;
    float* dis    = (float*)wsb;                      wsb += (size_t)N_NODES * 4;
    float* xws2   = (float*)wsb;                      wsb += (size_t)N_NODES * 4;
    float* x2     = (float*)wsb;                      wsb += (size_t)N_NODES * 4;
    int*   gstart = (int*)wsb;                        wsb += (size_t)(B_GRAPHS + 1) * 4;
    float* outp   = (float*)d_out;

    hipMemsetAsync(gcur, 0, (size_t)NBKT * 4, stream);

    k_mscatter<<<(N_EDGES + MS_EPB - 1) / MS_EPB, 256, 0, stream>>>(row, col, gcur, ebkt);
    k_csrw<<<NBKT, 256, 0, stream>>>(ebkt, gcur, bat, x, W1, dis, rowse, erow, gstart, xws);
    k_agg1m<<<N_NODES / 4, 256, 0, stream>>>(rowse, erow, xws, dis, b1, W2, x1, xws2);
    k_x2<<<N_NODES / (8 * 4), 256, 0, stream>>>(rowse, erow, xws2, dis, b2, x2);
    k_poolhead<<<B_GRAPHS, 256, 0, stream>>>(gstart, x1, x2,
                                             w3, b3, w4, b4, fw1, fb1, fw2, fb2, outp);
}

// Round 16
// 291.324 us; speedup vs baseline: 1.0580x; 1.0257x over previous
//
#include <hip/hip_runtime.h>
#include <math.h>

#define N_NODES 100000
#define N_EDGES 3200000
#define B_GRAPHS 500
#define K_TOP 30
#define F_INN 128
#define H1C 64
#define NUM_CLASSES 18
#define XC 65               // H1 + 1
#define P_LEN (K_TOP * XC)  // 1950
#define C3_OUT 16
#define C3_K 97
#define C3_L 20
#define P2_L 10
#define C4_OUT 32
#define C4_K 5
#define C4_L 6
#define FC1_IN 192
#define FC1_OUT 128

#define BK_SHIFT 7
#define BK_NODES 128                               // nodes per bucket
#define NBKT ((N_NODES + BK_NODES - 1) / BK_NODES) // 782
#define BSTRIDE 5120                               // slots per bucket (mean 4096 + 16 sigma)
#define MS_EPT 64                                  // edges per thread in mscatter
#define MS_EPB (256 * MS_EPT)                      // 16384 edges per block -> 196 blocks

#define REG_B 544                                  // bytes per (t,h) LDS region (512 + 32 skew)

typedef __attribute__((ext_vector_type(8))) short bf16x8;
typedef __attribute__((ext_vector_type(4))) float f32x4;
typedef __attribute__((ext_vector_type(2))) unsigned int u32x2;

// bf16 helpers
static __device__ __forceinline__ unsigned short f2bf(float f) {
    unsigned int u = __float_as_uint(f);
    u += 0x7FFFu + ((u >> 16) & 1u);   // round to nearest even
    return (unsigned short)(u >> 16);
}

// ------- multi-split scatter: ebkt[b*BSTRIDE + slot] = (row<<7 | col_local) -------
__global__ __launch_bounds__(256) void k_mscatter(const int* __restrict__ row,
                                                  const int* __restrict__ col,
                                                  int* __restrict__ gcur,
                                                  unsigned int* __restrict__ ebkt) {
    __shared__ int hist[NBKT];
    __shared__ int base[NBKT];
    int tid = threadIdx.x;
    for (int i = tid; i < NBKT; i += 256) hist[i] = 0;
    __syncthreads();
    unsigned int pk[MS_EPT];   // (bucket<<12) | rank, or sentinel
    unsigned int pay[MS_EPT];  // (row<<7) | col_local
    int e0q = blockIdx.x * (MS_EPB / 4);   // int4 index base
#pragma unroll
    for (int j = 0; j < MS_EPT / 4; ++j) {
        int q = e0q + j * 256 + tid;
        bool ok = (q * 4) < N_EDGES;       // N_EDGES % 4 == 0: all-or-nothing
        int4 r4 = ok ? ((const int4*)row)[q] : make_int4(0, 0, 0, 0);
        int4 c4 = ok ? ((const int4*)col)[q] : make_int4(0, 0, 0, 0);
#pragma unroll
        for (int k = 0; k < 4; ++k) {
            int jj = j * 4 + k;
            pk[jj] = 0xFFFFFFFFu;
            int r = k == 0 ? r4.x : k == 1 ? r4.y : k == 2 ? r4.z : r4.w;
            int c = k == 0 ? c4.x : k == 1 ? c4.y : k == 2 ? c4.z : c4.w;
            if (ok && r != c) {
                int b = c >> BK_SHIFT;
                int rank = atomicAdd(&hist[b], 1);
                pk[jj] = ((unsigned int)b << 12) | (unsigned int)rank;   // rank < 4096 (mean 21)
                pay[jj] = ((unsigned int)r << BK_SHIFT) | (unsigned int)(c & (BK_NODES - 1));
            }
        }
    }
    __syncthreads();
    for (int i = tid; i < NBKT; i += 256)
        base[i] = hist[i] ? (i * BSTRIDE + atomicAdd(&gcur[i], hist[i])) : 0;
    __syncthreads();
#pragma unroll
    for (int j = 0; j < MS_EPT; ++j) {
        if (pk[j] != 0xFFFFFFFFu) {
            int b = pk[j] >> 12;
            int rank = pk[j] & 0xFFF;
            ebkt[base[b] + rank] = pay[j];
        }
    }
}

// ------- merged CSR build + gstart table + xw1 MFMA (block-local fusion) -------
__global__ __launch_bounds__(256) void k_csrw(const unsigned int* __restrict__ ebkt,
                                              const int* __restrict__ gcur,
                                              const int* __restrict__ batch,
                                              const float* __restrict__ x,
                                              const float* __restrict__ W1,
                                              float* __restrict__ dis,
                                              int2* __restrict__ rowse,
                                              int* __restrict__ erow,
                                              int* __restrict__ gstart,
                                              unsigned short* __restrict__ xw) {
    __shared__ __align__(16) char ubuf[BSTRIDE * 4];   // 20480B: ebs, then w1s
    __shared__ int cnt[BK_NODES];
    __shared__ int s[256];
    __shared__ int cur[BK_NODES];
    __shared__ float diss[BK_NODES];
    int b = blockIdx.x, t = threadIdx.x;
    unsigned int* ebs = (unsigned int*)ubuf;
    if (t < BK_NODES) {
        cnt[t] = 0;
        int node = b * BK_NODES + t;
        if (node < N_NODES) {   // graph boundary marking (disjoint writes across blocks)
            int bc = batch[node];
            int bp = node ? batch[node - 1] : -1;
            for (int g = bp + 1; g <= bc; ++g) gstart[g] = node;
            if (node == N_NODES - 1)
                for (int g = bc + 1; g <= B_GRAPHS; ++g) gstart[g] = N_NODES;
        }
    }
    __syncthreads();
    int n = gcur[b];
    int lo = b * BSTRIDE;
    for (int i = t; i < n; i += 256) {
        unsigned int pk = ebkt[lo + i];
        ebs[i] = pk;
        atomicAdd(&cnt[pk & (BK_NODES - 1)], 1);
    }
    __syncthreads();
    int v = (t < BK_NODES) ? cnt[t] : 0;
    s[t] = v;
    __syncthreads();
    for (int off = 1; off < BK_NODES; off <<= 1) {
        int add = (t >= off) ? s[t - off] : 0;
        __syncthreads();
        s[t] += add;
        __syncthreads();
    }
    int ex = s[t] - v;
    if (t < BK_NODES) {
        float dv = rsqrtf((float)v + 1.0f);
        diss[t] = dv;
        int node = b * BK_NODES + t;
        if (node < N_NODES) {
            dis[node] = dv;
            rowse[node] = make_int2(lo + ex, lo + ex + v);
        }
        cur[t] = lo + ex;
    }
    __syncthreads();
    for (int i = t; i < n; i += 256) {
        unsigned int pk = ebs[i];
        int cl = pk & (BK_NODES - 1);
        int slot = atomicAdd(&cur[cl], 1);
        erow[slot] = (int)((pk >> BK_SHIFT) << 7);   // byte offset into bf16 rows (128B)
    }
    __syncthreads();   // ebs dead: safe to overwrite with w1s
    // ---- xw1 phase: xws rows for this block's 128 nodes ----
    unsigned short* w1s = (unsigned short*)ubuf;   // 16KB
    if (b == 0 && t < 32)
        ((unsigned int*)(xw + (size_t)N_NODES * H1C))[t] = 0;   // zero pad row
    for (int idx = t; idx < 16 * 64 * 8; idx += 256) {
        int f = idx >> 9;
        int l = (idx >> 3) & 63;
        int j = idx & 7;
        int kq = f >> 2, t4 = f & 3;
        int k = kq * 32 + ((l >> 4) << 3) + j;
        int nn = t4 * 16 + (l & 15);
        w1s[idx] = f2bf(W1[k * H1C + nn]);
    }
    __syncthreads();
    int wave = t >> 6;
    int lane = t & 63;
    int quad = lane >> 4;
    int m = lane & 15;

    bf16x8 bw[16];
#pragma unroll
    for (int f = 0; f < 16; ++f)
        bw[f] = *(const bf16x8*)&w1s[(f * 64 + lane) * 8];

#pragma unroll
    for (int rt = 0; rt < 2; ++rt) {
        int wrow0 = b * BK_NODES + rt * 64 + wave * 16;
        f32x4 acc[4];
#pragma unroll
        for (int tt = 0; tt < 4; ++tt) acc[tt] = (f32x4){0.f, 0.f, 0.f, 0.f};

        int rowA = wrow0 + m;
        size_t ra = (size_t)(rowA < N_NODES ? rowA : N_NODES - 1);
#pragma unroll
        for (int kq = 0; kq < 4; ++kq) {
            const float* xp = x + ra * F_INN + kq * 32 + quad * 8;
            float4 f0 = ((const float4*)xp)[0];
            float4 f1 = ((const float4*)xp)[1];
            bf16x8 a;
            a[0] = (short)f2bf(f0.x); a[1] = (short)f2bf(f0.y);
            a[2] = (short)f2bf(f0.z); a[3] = (short)f2bf(f0.w);
            a[4] = (short)f2bf(f1.x); a[5] = (short)f2bf(f1.y);
            a[6] = (short)f2bf(f1.z); a[7] = (short)f2bf(f1.w);
#pragma unroll
            for (int tt = 0; tt < 4; ++tt)
                acc[tt] = __builtin_amdgcn_mfma_f32_16x16x32_bf16(a, bw[kq * 4 + tt], acc[tt], 0, 0, 0);
        }
#pragma unroll
        for (int r = 0; r < 4; ++r) {
            int rowD = wrow0 + quad * 4 + r;
            if (rowD < N_NODES) {
                float dsc = diss[rowD - b * BK_NODES];
#pragma unroll
                for (int tt = 0; tt < 4; ++tt)
                    xw[(size_t)rowD * H1C + tt * 16 + m] = f2bf(acc[tt][r] * dsc);
            }
        }
    }
}

// ------- conv1 gather via MFMA aggregation (R7-proven non-pipelined form) -------
__global__ __launch_bounds__(256) void k_agg1m(const int2* __restrict__ rowse,
                                               const int* __restrict__ erow,
                                               const unsigned short* __restrict__ xws,
                                               const float* __restrict__ dis,
                                               const float* __restrict__ b1,
                                               const float* __restrict__ W2,
                                               float* __restrict__ x1,
                                               float* __restrict__ xws2) {
    __shared__ __align__(16) char slds[4][8 * REG_B];   // 17408 B
    int tid = threadIdx.x;
    int wave = tid >> 6;
    int lane = tid & 63;
    int wid = blockIdx.x * 4 + wave;   // wid < N_NODES always (exact grid)
    int grp = lane >> 3;   // 0..7  -> edge-within-octet
    int sub = lane & 7;    // 0..7  -> 16B chunk of the 128B row
    int2 se = rowse[wid];
    int base = se.x, endp = se.y;
    int nE = endp - base;
    const char* xb = (const char*)xws;
    const int ZR = N_NODES << 7;   // zero row pad (L1-cached)

    char* wreg = &slds[wave][0];
    char* dst0 = wreg + ((sub >> 1) * 2 + ((grp >> 2) & 1)) * REG_B + (grp & 3) * 32 + (sub & 1) * 16;
    unsigned int trb = (unsigned int)(size_t)wreg +
                       (unsigned int)(((lane >> 4) * 64 + (lane & 15)) * 2);

    bf16x8 aones;
#pragma unroll
    for (int i = 0; i < 8; ++i) aones[i] = (short)0x3F80;   // bf16 1.0

    f32x4 ac0 = (f32x4){0.f, 0.f, 0.f, 0.f};
    f32x4 ac1 = ac0, ac2 = ac0, ac3 = ac0;

    for (int w0 = 0; w0 < nE; w0 += 64) {
        int idx = base + w0 + lane;
        int myoff = (idx < endp) ? erow[idx] : ZR;
#pragma unroll
        for (int hf = 0; hf < 2; ++hf) {
            if (w0 + hf * 32 < nE) {   // wave-uniform
#pragma unroll
                for (int ii = 0; ii < 4; ++ii) {
                    int o = __shfl(myoff, hf * 32 + ii * 8 + grp);
                    uint4 v = ((const uint4*)(xb + o))[sub];
                    *(uint4*)(dst0 + ii * 128) = v;
                }
                asm volatile("s_waitcnt lgkmcnt(0)" ::: "memory");
                __builtin_amdgcn_sched_barrier(0);
                u32x2 q0, q1, q2, q3, q4, q5, q6, q7;
                asm volatile("ds_read_b64_tr_b16 %0, %1 offset:0"    : "=v"(q0) : "v"(trb) : "memory");
                asm volatile("ds_read_b64_tr_b16 %0, %1 offset:544"  : "=v"(q1) : "v"(trb) : "memory");
                asm volatile("ds_read_b64_tr_b16 %0, %1 offset:1088" : "=v"(q2) : "v"(trb) : "memory");
                asm volatile("ds_read_b64_tr_b16 %0, %1 offset:1632" : "=v"(q3) : "v"(trb) : "memory");
                asm volatile("ds_read_b64_tr_b16 %0, %1 offset:2176" : "=v"(q4) : "v"(trb) : "memory");
                asm volatile("ds_read_b64_tr_b16 %0, %1 offset:2720" : "=v"(q5) : "v"(trb) : "memory");
                asm volatile("ds_read_b64_tr_b16 %0, %1 offset:3264" : "=v"(q6) : "v"(trb) : "memory");
                asm volatile("ds_read_b64_tr_b16 %0, %1 offset:3808" : "=v"(q7) : "v"(trb) : "memory");
                asm volatile("s_waitcnt lgkmcnt(0)" ::: "memory");
                __builtin_amdgcn_sched_barrier(0);
                union FU { bf16x8 f; unsigned int d[4]; };
                FU f0, f1, f2, f3;
                f0.d[0] = q0.x; f0.d[1] = q0.y; f0.d[2] = q1.x; f0.d[3] = q1.y;
                f1.d[0] = q2.x; f1.d[1] = q2.y; f1.d[2] = q3.x; f1.d[3] = q3.y;
                f2.d[0] = q4.x; f2.d[1] = q4.y; f2.d[2] = q5.x; f2.d[3] = q5.y;
                f3.d[0] = q6.x; f3.d[1] = q6.y; f3.d[2] = q7.x; f3.d[3] = q7.y;
                ac0 = __builtin_amdgcn_mfma_f32_16x16x32_bf16(aones, f0.f, ac0, 0, 0, 0);
                ac1 = __builtin_amdgcn_mfma_f32_16x16x32_bf16(aones, f1.f, ac1, 0, 0, 0);
                ac2 = __builtin_amdgcn_mfma_f32_16x16x32_bf16(aones, f2.f, ac2, 0, 0, 0);
                ac3 = __builtin_amdgcn_mfma_f32_16x16x32_bf16(aones, f3.f, ac3, 0, 0, 0);
            }
        }
    }
    float v0s = __shfl(ac0[0], lane & 15);
    float v1s = __shfl(ac1[0], lane & 15);
    float v2s = __shfl(ac2[0], lane & 15);
    float v3s = __shfl(ac3[0], lane & 15);
    int ts = lane >> 4;
    float aggv = ts == 0 ? v0s : (ts == 1 ? v1s : (ts == 2 ? v2s : v3s));
    float d = dis[wid];
    unsigned int su = xws[(size_t)wid * H1C + lane];   // self row (pre-scaled by dis[wid])
    float self = __uint_as_float(su << 16);
    float v = tanhf(d * (aggv + self) + b1[lane]);
    x1[(size_t)wid * H1C + lane] = v;
    float s = v * W2[lane];
#pragma unroll
    for (int off = 1; off < 64; off <<= 1) s += __shfl_xor(s, off);
    if (lane == 0) xws2[wid] = d * s;   // pre-scaled by dis
}

// ------- fused conv2 + sort-pool + head: one block per graph (R12 base) -------
// conv2 uses static unrolled clamped-address gathers: 8 independent erow/xws2
// load pairs in flight per lane (covers deg<=64 branch-free); rare deg>64 tail.
// Per-lane addition order identical to the R12 sequential loop.
__global__ __launch_bounds__(256) void k_poolhead(const int* __restrict__ gstart,
                                                  const float* __restrict__ x1,
                                                  const int2* __restrict__ rowse,
                                                  const int* __restrict__ erow,
                                                  const float* __restrict__ xws2,
                                                  const float* __restrict__ dis,
                                                  const float* __restrict__ b2,
                                                  const float* __restrict__ w3, const float* __restrict__ b3,
                                                  const float* __restrict__ w4, const float* __restrict__ b4,
                                                  const float* __restrict__ fw1, const float* __restrict__ fb1,
                                                  const float* __restrict__ fw2, const float* __restrict__ fb2,
                                                  float* __restrict__ out) {
    __shared__ float x2s[512];
    __shared__ int sel[K_TOP];
    __shared__ float ps[P_LEN];
    __shared__ float h1s[C3_OUT * C3_L];
    __shared__ float h2s[C3_OUT * P2_L];
    __shared__ float h3s[FC1_IN];
    __shared__ float lls[FC1_OUT];
    __shared__ float outs[NUM_CLASSES];
    int g = blockIdx.x, tid = threadIdx.x;
    int start = gstart[g];
    int end = gstart[g + 1];
    int count = end - start;
    if (count > 512) count = 512;
    int wave = tid >> 6, lane = tid & 63;
    // conv2: 4 waves x 8 nodes/wave, 8 lanes per node; 8-deep independent gathers
    {
        float b2v = b2[0];
        int grp8 = lane >> 3, sub8 = lane & 7;
        for (int t0 = 0; t0 < count; t0 += 32) {
            int li = t0 + wave * 8 + grp8;
            float acc = 0.0f;
            int node = start + li;
            if (li < count) {
                int2 se = rowse[node];
                int bs = se.x, ep = se.y;
                int i0 = bs + sub8;
                int last = ep - 1;
#pragma unroll
                for (int k = 0; k < 8; ++k) {   // 8 independent load pairs in flight
                    int i = i0 + k * 8;
                    int ic = (i <= last) ? i : (last >= bs ? bs : 0);   // clamped, always valid
                    float vv = xws2[erow[ic] >> 7];
                    acc += (i < ep) ? vv : 0.0f;
                }
                for (int i = i0 + 64; i < ep; i += 8)   // rare deg>64 tail
                    acc += xws2[erow[i] >> 7];
            }
            acc += __shfl_xor(acc, 1);
            acc += __shfl_xor(acc, 2);
            acc += __shfl_xor(acc, 4);
            if (li < count && sub8 == 0)
                x2s[li] = tanhf(dis[node] * (acc + xws2[node]) + b2v);
        }
    }
    __syncthreads();
    if (wave == 0) {
        unsigned long long k[8];
#pragma unroll
        for (int i = 0; i < 8; ++i) {
            int idx = i * 64 + lane;
            unsigned long long key = 0ULL;
            if (idx < count) {
                unsigned int bits = __float_as_uint(x2s[idx]);
                unsigned int u = (bits & 0x80000000u) ? ~bits : (bits | 0x80000000u);
                key = ((unsigned long long)u << 32) | (unsigned int)(~(unsigned int)(start + idx));
            }
            k[i] = key;
        }
        int kk = count < K_TOP ? count : K_TOP;
        for (int j = 0; j < kk; ++j) {
            unsigned long long best = k[0];
#pragma unroll
            for (int i = 1; i < 8; ++i) if (k[i] > best) best = k[i];
#pragma unroll
            for (int off = 32; off; off >>= 1) {
                unsigned long long o = __shfl_xor(best, off);
                if (o > best) best = o;
            }
            int node = (int)(~(unsigned int)(best & 0xFFFFFFFFULL));
#pragma unroll
            for (int i = 0; i < 8; ++i) if (k[i] == best) k[i] = 0ULL;
            if (lane == 0) sel[j] = node;
        }
        if (lane >= kk && lane < K_TOP) sel[lane] = -1;
    }
    __syncthreads();
    for (int t = tid; t < P_LEN; t += 256) {
        int j = t / XC, c = t - j * XC;
        int node = sel[j];
        float v = 0.0f;
        if (node >= 0) v = (c < H1C) ? x1[(size_t)node * H1C + c] : x2s[node - start];
        ps[t] = v;
    }
    __syncthreads();
    for (int o = tid; o < C3_OUT * C3_L; o += 256) {
        int oc = o / C3_L, pos = o % C3_L;
        float s = b3[oc];
        const float* w = w3 + oc * C3_K;
        int base = pos * C3_K;
        for (int k = 0; k < C3_K; ++k) s += ps[base + k] * w[k];
        h1s[o] = fmaxf(s, 0.0f);
    }
    __syncthreads();
    if (tid < C3_OUT * P2_L) {
        int oc = tid / P2_L, pos = tid % P2_L;
        h2s[tid] = fmaxf(h1s[oc * C3_L + 2 * pos], h1s[oc * C3_L + 2 * pos + 1]);
    }
    __syncthreads();
    if (tid < C4_OUT * C4_L) {
        int oc = tid / C4_L, pos = tid % C4_L;
        float s = b4[oc];
        for (int ic = 0; ic < C3_OUT; ++ic)
#pragma unroll
            for (int k = 0; k < C4_K; ++k)
                s += h2s[ic * P2_L + pos + k] * w4[oc * C3_OUT * C4_K + ic * C4_K + k];
        h3s[oc * C4_L + pos] = fmaxf(s, 0.0f);
    }
    __syncthreads();
    if (tid < FC1_OUT) {
        float s = fb1[tid];
        for (int i = 0; i < FC1_IN; ++i) s += h3s[i] * fw1[i * FC1_OUT + tid];
        float v = fmaxf(s, 0.0f);
        lls[tid] = v;
        out[2 * B_GRAPHS * NUM_CLASSES + (size_t)g * FC1_OUT + tid] = v;
    }
    __syncthreads();
    if (tid < NUM_CLASSES) {
        float s = fb2[tid];
        for (int j = 0; j < FC1_OUT; ++j) s += lls[j] * fw2[j * NUM_CLASSES + tid];
        outs[tid] = s;
        out[B_GRAPHS * NUM_CLASSES + (size_t)g * NUM_CLASSES + tid] = s;
    }
    __syncthreads();
    if (tid < NUM_CLASSES) {
        float m = -INFINITY;
        for (int k2 = 0; k2 < NUM_CLASSES; ++k2) m = fmaxf(m, outs[k2]);
        float se = 0.0f;
        for (int k2 = 0; k2 < NUM_CLASSES; ++k2) se += expf(outs[k2] - m);
        out[(size_t)g * NUM_CLASSES + tid] = outs[tid] - m - logf(se);
    }
}

extern "C" void kernel_launch(void* const* d_in, const int* in_sizes, int n_in,
                              void* d_out, int out_size, void* d_ws, size_t ws_size,
                              hipStream_t stream) {
    const float* x   = (const float*)d_in[0];
    const int*   ei  = (const int*)d_in[1];
    const int*   row = ei;
    const int*   col = ei + N_EDGES;
    const int*   bat = (const int*)d_in[2];
    const float* W1  = (const float*)d_in[4];
    const float* b1  = (const float*)d_in[5];
    const float* W2  = (const float*)d_in[6];
    const float* b2  = (const float*)d_in[7];
    const float* w3  = (const float*)d_in[8];
    const float* b3  = (const float*)d_in[9];
    const float* w4  = (const float*)d_in[10];
    const float* b4  = (const float*)d_in[11];
    const float* fw1 = (const float*)d_in[12];
    const float* fb1 = (const float*)d_in[13];
    const float* fw2 = (const float*)d_in[14];
    const float* fb2 = (const float*)d_in[15];

    char* wsb = (char*)d_ws;
    unsigned short* xws = (unsigned short*)wsb;       wsb += (size_t)(N_NODES + 1) * H1C * 2; // 12.8 MB (+zero row)
    float* x1     = (float*)wsb;                      wsb += (size_t)N_NODES * H1C * 4;       // 25.6 MB
    int*   erow   = (int*)wsb;                        wsb += (size_t)NBKT * BSTRIDE * 4;      // 16.0 MB
    // ebkt aliases x1 (16.0 MB <= 25.6 MB): consumed by k_csrw before k_agg1m writes x1
    unsigned int* ebkt = (unsigned int*)x1;
    int*   gcur   = (int*)wsb;                        wsb += (size_t)NBKT * 4;
    int2*  rowse  = (int2*)wsb;                       wsb += (size_t)N_NODES * 8;
    float* dis    = (float*)wsb;                      wsb += (size_t)N_NODES * 4;
    float* xws2   = (float*)wsb;                      wsb += (size_t)N_NODES * 4;
    int*   gstart = (int*)wsb;                        wsb += (size_t)(B_GRAPHS + 1) * 4;
    float* outp   = (float*)d_out;

    hipMemsetAsync(gcur, 0, (size_t)NBKT * 4, stream);

    k_mscatter<<<(N_EDGES + MS_EPB - 1) / MS_EPB, 256, 0, stream>>>(row, col, gcur, ebkt);
    k_csrw<<<NBKT, 256, 0, stream>>>(ebkt, gcur, bat, x, W1, dis, rowse, erow, gstart, xws);
    k_agg1m<<<N_NODES / 4, 256, 0, stream>>>(rowse, erow, xws, dis, b1, W2, x1, xws2);
    k_poolhead<<<B_GRAPHS, 256, 0, stream>>>(gstart, x1, rowse, erow, xws2, dis, b2,
                                             w3, b3, w4, b4, fw1, fb1, fw2, fb2, outp);
}